// Round 1
// baseline (45.697 us; speedup 1.0000x reference)
//
#include <hip/hip_runtime.h>

// out[b, f] = x[b, f] * exp(diagonal[f])
// x: 8192 x 4096 f32, diagonal: 4096 f32, out: 8192 x 4096 f32.
// Memory-bound elementwise op. float4 vectorization, exp() hoisted out of
// the row loop (each thread owns a fixed column quad across 16 rows).

#define ROWS 8192
#define COLS 4096
#define ROW_F4 (COLS / 4)          // 1024 float4 per row
#define BLOCK 256
#define GRID_X (ROW_F4 / BLOCK)    // 4 column blocks cover a full row
#define GRID_Y 512                 // 2048 blocks total; 16 rows per thread

__global__ __launch_bounds__(BLOCK) void Diagonal_73126113181894_kernel(
    const float4* __restrict__ x, const float* __restrict__ diagonal,
    float4* __restrict__ out) {
  const int col4 = blockIdx.x * BLOCK + threadIdx.x;   // float4 column index
  // Load this thread's 4 diagonal values once, exp once, reuse for all rows.
  const float4 d = reinterpret_cast<const float4*>(diagonal)[col4];
  float4 e;
  e.x = expf(d.x);
  e.y = expf(d.y);
  e.z = expf(d.z);
  e.w = expf(d.w);

  for (int r = blockIdx.y; r < ROWS; r += GRID_Y) {
    const size_t idx = (size_t)r * ROW_F4 + col4;
    float4 v = x[idx];
    v.x *= e.x;
    v.y *= e.y;
    v.z *= e.z;
    v.w *= e.w;
    out[idx] = v;
  }
}

extern "C" void kernel_launch(void* const* d_in, const int* in_sizes, int n_in,
                              void* d_out, int out_size, void* d_ws, size_t ws_size,
                              hipStream_t stream) {
  const float4* x = (const float4*)d_in[0];
  const float* diagonal = (const float*)d_in[1];
  float4* out = (float4*)d_out;

  dim3 grid(GRID_X, GRID_Y, 1);
  dim3 block(BLOCK, 1, 1);
  Diagonal_73126113181894_kernel<<<grid, block, 0, stream>>>(x, diagonal, out);
}